// Round 14
// baseline (596.746 us; speedup 1.0000x reference)
//
#include <hip/hip_runtime.h>
#include <math.h>

// Problem constants (fixed by the reference)
#define B_ 4
#define T_ 2048
#define D_ 2048
#define L_ 2048
#define KW 4
#define M_ (B_*T_)       // 8192 rows for all GEMMs

typedef unsigned short u16;
typedef unsigned short u16x8 __attribute__((ext_vector_type(8)));
typedef __bf16 bf16x8 __attribute__((ext_vector_type(8)));
typedef float f32x4 __attribute__((ext_vector_type(4)));

__device__ __forceinline__ u16 f2bf(float f) {       // RNE f32 -> bf16 bits
    unsigned u = __float_as_uint(f);
    u += 0x7fffu + ((u >> 16) & 1u);
    return (u16)(u >> 16);
}
__device__ __forceinline__ float bf2f(u16 h) {
    return __uint_as_float(((unsigned)h) << 16);
}
__device__ __forceinline__ float gelu_exact(float v) {
    return 0.5f * v * (1.0f + erff(v * 0.70710678118654752440f));
}
__device__ __forceinline__ float sigmoidf_(float v) {
    return 1.0f / (1.0f + __expf(-v));
}
__device__ __forceinline__ void gload16(const void* g, void* l) {
    __builtin_amdgcn_global_load_lds(
        (const __attribute__((address_space(1))) void*)g,
        (__attribute__((address_space(3))) void*)l,
        16, 0, 0);
}
__device__ __forceinline__ void bar() {
    __builtin_amdgcn_s_barrier();
}

// ---------------- cast x -> bf16 ----------------
__global__ __launch_bounds__(256)
void castx_kernel(const float* __restrict__ in, u16* __restrict__ out)
{
    const int i = blockIdx.x * 256 + threadIdx.x;      // one float4
    float4 v = ((const float4*)in)[i];
    ushort4 o;
    o.x = f2bf(v.x); o.y = f2bf(v.y); o.z = f2bf(v.z); o.w = f2bf(v.w);
    ((ushort4*)out)[i] = o;
}

// ---------------- transpose-cast weight [K,N] f32 -> [N,K] bf16 ----------------
__global__ __launch_bounds__(256)
void transcast_kernel(const float* __restrict__ in, u16* __restrict__ out,
                      int Kd, int Nd)
{
    __shared__ float tile[32][33];
    const int bx = blockIdx.x;          // along N
    const int by = blockIdx.y;          // along K
    const int tx = threadIdx.x & 31;
    const int ty = threadIdx.x >> 5;    // 0..7
    #pragma unroll
    for (int j = 0; j < 4; ++j) {
        const int r = by*32 + ty + j*8;
        tile[ty + j*8][tx] = in[(size_t)r * Nd + bx*32 + tx];
    }
    __syncthreads();
    #pragma unroll
    for (int j = 0; j < 4; ++j) {
        const int n = bx*32 + ty + j*8;
        out[(size_t)n * Kd + by*32 + tx] = f2bf(tile[tx][ty + j*8]);
    }
}

// =====================================================================
// bf16 MFMA GEMM — round 14: r12 structure (16x16x32, verified swizzle,
// 0 conflicts) + IN-WAVE FRAGMENT PIPELINING.
// r13 lesson: the 32x32 fragment read pattern bank-conflicts (8.4M) —
// reverted. r12's residual loss: reads serialize ahead of MFMA inside
// each iter (barrier blocks cross-iter hoisting). Fix: ping-pong frag
// sets; body g reads frags(g+1) AFTER the mid-bar and BEFORE MFMA(g),
// so the 8 b128 reads stream in the LDS pipe under the 16-MFMA cluster;
// MFMA(g) is gated only by the compiler's precise operand-lgkm on the
// PREVIOUS body's reads. acc=64 so 2nd frag set (+32 VGPR) stays well
// under the 256 cliff (r9 spilled at acc=128 + dual frags).
//
// Body g: [STAGE(g+2) | vmcnt(3) | bar | LDFRAG(g+1)->next | MFMA(g) on
//          cur | bar2], unrolled x2 with named P/Q sets (rule #20).
// vmcnt ledger (3 gloads/body): at body g's vmcnt: outstanding =
//   STAGE(g+1)[3, body g-1] + STAGE(g+2)[3, just issued] = 6 -> vmcnt(3)
//   retires STAGE(g+1), BEFORE mid-bar -> LDFRAG(g+1) cross-wave safe
//   (r5 lesson). Tail: g=NT-2 -> vmcnt(0); g=NT-1 -> nothing.
// WAR ledger: STAGE(g+2) overwrites slot (g+2)%3=(g-1)%3; its readers =
//   LDFRAG(g-1) (body g-2), completion FORCED by MFMA(g-1)'s operand
//   wait (body g-1) which precedes bar2(g-1); STAGE(g+2) at body g
//   follows bar2(g-1) -> safe for ALL waves.
// Swizzle = r12 verified (0 conflicts): stage pre-swizzled global slot
// (lane&3)^((lane>>3)&3), linear dest; read slot q^((lr>>1)&3).
//
// EPI: 0 = bias, 1 = gelu,
//      3 = RG-LRU "a":  g2=sig(v); a = (t==0)?0:exp(-8*g2*softplus(ap[col]))
//      4 = RG-LRU "nx": gx=sig(v); a=auxA[idx]; cv=auxC[idx];
//                       nx = gx*cv*sqrt(1-a^2)   (t==0: a==0 -> mult=1)
// =====================================================================
__device__ __forceinline__ void store_out(float* C, size_t idx, float v) { C[idx] = v; }
__device__ __forceinline__ void store_out(u16*   C, size_t idx, float v) { C[idx] = f2bf(v); }

template<int EPI, typename OutT>
__global__ __launch_bounds__(512)
void mgemm_kernel(const u16* __restrict__ A, const u16* __restrict__ BT,
                  const float* __restrict__ bias, OutT* __restrict__ C,
                  int M, int N, int K,
                  const u16* __restrict__ auxA,   // EPI=4: a buffer
                  const u16* __restrict__ auxC,   // EPI=4: conv buffer
                  const float* __restrict__ ap)   // EPI=3: a_param
{
    __shared__ __align__(16) u16 lds[36864];   // A: 3x8192 u16 | B: 3x4096 u16 = 72 KB
    u16* ldsB = lds + 24576;

    const int tid  = threadIdx.x;
    const int wave = tid >> 6;          // 0..7
    const int lane = tid & 63;

    // bijective XCD swizzle (nwg = 512, %8 == 0)
    const int nbx = N >> 7;                       // N/128
    const int nwg = nbx * (M >> 8);
    const int bid = blockIdx.x;
    const int li  = (bid & 7) * (nwg >> 3) + (bid >> 3);
    const int bm  = (li / nbx) * 256;
    const int bn  = (li % nbx) * 128;

    const int wr = wave >> 1;           // 0..3 (M quarter: 64 rows)
    const int wn = wave & 1;            // 0..1 (N half: 64 cols)
    const int lr = lane & 15;
    const int q  = lane >> 4;

    const int grow  = lane >> 2;                       // row within chunk
    const int gslot = (lane & 3) ^ ((lane >> 3) & 3);  // pre-swizzled k-slot
    const u16* gA0 = A  + (size_t)(bm + wave*16     + grow) * K + gslot*8;
    const u16* gA1 = A  + (size_t)(bm + (wave+8)*16 + grow) * K + gslot*8;
    const u16* gB0 = BT + (size_t)(bn + wave*16     + grow) * K + gslot*8;
    const int dA0 = wave*512     + lane*8;
    const int dA1 = (wave+8)*512 + lane*8;
    const int dB0 = wave*512     + lane*8;

    auto STAGE = [&](int g) {
        const int s = g % 3;
        const size_t kg = (size_t)g << 5;
        u16* a = lds  + s*8192;
        u16* b = ldsB + s*4096;
        gload16(gA0 + kg, &a[dA0]);
        gload16(gA1 + kg, &a[dA1]);
        gload16(gB0 + kg, &b[dB0]);
    };

    const int ksw = (q ^ ((lr >> 1) & 3)) * 8;   // read-side swizzled k-slot

    f32x4 acc[4][4] = {};
    bf16x8 aP[4], bP[4], aQ[4], bQ[4];           // ping-pong fragment sets

    auto LDFRAG = [&](int g, bf16x8 (&af)[4], bf16x8 (&bf)[4]) {
        const int s = g % 3;
        const u16* Ab = lds  + s*8192;
        const u16* Bb = ldsB + s*4096;
        #pragma unroll
        for (int i = 0; i < 4; ++i)
            af[i] = *(const bf16x8*)&Ab[(wr*64 + i*16 + lr)*32 + ksw];
        #pragma unroll
        for (int j = 0; j < 4; ++j)
            bf[j] = *(const bf16x8*)&Bb[(wn*64 + j*16 + lr)*32 + ksw];
    };

    auto MM = [&](bf16x8 (&af)[4], bf16x8 (&bf)[4]) {
        __builtin_amdgcn_s_setprio(1);
        #pragma unroll
        for (int i = 0; i < 4; ++i)
            #pragma unroll
            for (int j = 0; j < 4; ++j)
                acc[i][j] = __builtin_amdgcn_mfma_f32_16x16x32_bf16(af[i], bf[j], acc[i][j], 0, 0, 0);
        __builtin_amdgcn_s_setprio(0);
    };

    const int NT = K >> 5;              // 64 K-tiles (even)

    // ---- prologue ----
    STAGE(0); STAGE(1);
    asm volatile("s_waitcnt vmcnt(3)" ::: "memory");   // retire tile 0 (before bar)
    bar();
    LDFRAG(0, aP, bP);

    #define BODY(GG, CURA, CURB, NXTA, NXTB)                                  \
    {                                                                         \
        const int gg = (GG);                                                  \
        if (gg + 2 < NT) STAGE(gg + 2);                                       \
        if (gg + 2 < NT)      { asm volatile("s_waitcnt vmcnt(3)" ::: "memory"); } \
        else if (gg + 1 < NT) { asm volatile("s_waitcnt vmcnt(0)" ::: "memory"); } \
        bar();                                                                \
        if (gg + 1 < NT) LDFRAG(gg + 1, NXTA, NXTB);                          \
        MM(CURA, CURB);                                                       \
        bar();                                                                \
    }

    for (int g = 0; g < NT; g += 2) {
        BODY(g,     aP, bP, aQ, bQ);
        BODY(g + 1, aQ, bQ, aP, bP);
    }
    #undef BODY

    // ---- epilogue; C/D layout: col = lane&15, row = (lane>>4)*4 + reg ----
    const int orow = (lane >> 4) * 4;
    float bv[4], spv[4];
    #pragma unroll
    for (int nj = 0; nj < 4; ++nj) {
        const int col = bn + wn*64 + nj*16 + lr;
        bv[nj] = bias[col];
        if (EPI == 3) spv[nj] = log1pf(expf(ap[col]));   // softplus(a_param)
    }
    #pragma unroll
    for (int mi = 0; mi < 4; ++mi) {
        #pragma unroll
        for (int r = 0; r < 4; ++r) {
            const int row = bm + wr*64 + mi*16 + orow + r;
            const size_t rb = (size_t)row * N + bn + wn*64 + lr;
            const int t = row & (T_ - 1);
            #pragma unroll
            for (int nj = 0; nj < 4; ++nj) {
                float v = acc[mi][nj][r] + bv[nj];
                if (EPI == 1) {
                    v = gelu_exact(v);
                } else if (EPI == 3) {
                    const float g2 = sigmoidf_(v);
                    v = (t == 0) ? 0.f : expf(-8.0f * g2 * spv[nj]);
                } else if (EPI == 4) {
                    const float gx = sigmoidf_(v);
                    const float av = bf2f(auxA[rb + nj*16]);
                    const float cv = bf2f(auxC[rb + nj*16]);
                    v = gx * cv * sqrtf(fmaxf(0.f, 1.0f - av*av));
                }
                store_out(C, rb + nj*16, v);
            }
        }
    }
}

// ---------------- causal depthwise conv1d, width 4 (bf16 in/out) ----------------
__global__ __launch_bounds__(256)
void conv_kernel(const u16* __restrict__ xb, const float* __restrict__ cw,
                 const float* __restrict__ cb, u16* __restrict__ out)
{
    const int idx = blockIdx.x * 256 + threadIdx.x;    // one 8-elem chunk
    const int NL8 = L_ / 8;
    const int l = (idx % NL8) * 8;
    const int bt = idx / NL8;
    const int t = bt & (T_ - 1);
    float acc[8];
    #pragma unroll
    for (int j = 0; j < 8; ++j) acc[j] = cb[l + j];
    #pragma unroll
    for (int k = 0; k < KW; ++k) {
        const int ts = t - (KW-1) + k;
        if (ts >= 0) {
            u16x8 xv = *(const u16x8*)(xb + ((size_t)(bt - (KW-1-k))) * L_ + l);
            #pragma unroll
            for (int j = 0; j < 8; ++j)
                acc[j] = fmaf(cw[k*L_ + l + j], bf2f(xv[j]), acc[j]);
        }
    }
    u16x8 o;
    #pragma unroll
    for (int j = 0; j < 8; ++j) o[j] = f2bf(acc[j]);
    *(u16x8*)(out + (size_t)bt * L_ + l) = o;
}

// ---------------- chunked linear scan: h_t = a_t*h_{t-1} + x_t ----------------
#define CHUNKS 32
#define CLEN (T_ / CHUNKS)   // 64

__global__ __launch_bounds__(256)
void scan1_kernel(const u16* __restrict__ Ab, const u16* __restrict__ Xb,
                  float* __restrict__ Pb, float* __restrict__ Sb)
{
    const int l = blockIdx.x * 256 + threadIdx.x;
    const int c = blockIdx.y;
    const int b = blockIdx.z;
    size_t base = ((size_t)b * T_ + (size_t)c * CLEN) * L_ + l;
    float h = 0.f, P = 1.f;
    #pragma unroll 4
    for (int t = 0; t < CLEN; ++t) {
        float a = bf2f(Ab[base + (size_t)t * L_]);
        float x = bf2f(Xb[base + (size_t)t * L_]);
        h = fmaf(a, h, x);
        P *= a;
    }
    const size_t o = ((size_t)b * CHUNKS + c) * L_ + l;
    Pb[o] = P;
    Sb[o] = h;
}

__global__ __launch_bounds__(256)
void scan2_kernel(const float* __restrict__ Pb, const float* __restrict__ Sb,
                  float* __restrict__ Hin, float* __restrict__ hn)
{
    const int idx = blockIdx.x * 256 + threadIdx.x;  // B*L threads
    const int l = idx & (L_ - 1);
    const int b = idx >> 11;
    float h = 0.f;
    for (int c = 0; c < CHUNKS; ++c) {
        const size_t o = ((size_t)b * CHUNKS + c) * L_ + l;
        Hin[o] = h;
        h = fmaf(Pb[o], h, Sb[o]);
    }
    hn[(size_t)b * L_ + l] = h;
}

__global__ __launch_bounds__(256)
void scan3_kernel(const u16* __restrict__ Ab, const u16* __restrict__ Xb,
                  const float* __restrict__ Hin, const u16* __restrict__ Yb,
                  u16* __restrict__ Zb)
{
    const int l = blockIdx.x * 256 + threadIdx.x;
    const int c = blockIdx.y;
    const int b = blockIdx.z;
    float h = Hin[((size_t)b * CHUNKS + c) * L_ + l];
    size_t base = ((size_t)b * T_ + (size_t)c * CLEN) * L_ + l;
    #pragma unroll 4
    for (int t = 0; t < CLEN; ++t) {
        const size_t o = base + (size_t)t * L_;
        h = fmaf(bf2f(Ab[o]), h, bf2f(Xb[o]));
        Zb[o] = f2bf(h * bf2f(Yb[o]));
    }
}

// ---------------- launch ----------------
extern "C" void kernel_launch(void* const* d_in, const int* in_sizes, int n_in,
                              void* d_out, int out_size, void* d_ws, size_t ws_size,
                              hipStream_t stream)
{
    const float* x     = (const float*)d_in[0];
    const float* w_y   = (const float*)d_in[1];
    const float* b_y   = (const float*)d_in[2];
    const float* w_x   = (const float*)d_in[3];
    const float* b_x   = (const float*)d_in[4];
    const float* cw    = (const float*)d_in[5];
    const float* cb    = (const float*)d_in[6];
    const float* ap    = (const float*)d_in[7];
    const float* w_ig  = (const float*)d_in[8];
    const float* b_ig  = (const float*)d_in[9];
    const float* w_ag  = (const float*)d_in[10];
    const float* b_ag  = (const float*)d_in[11];
    const float* w_out = (const float*)d_in[12];
    const float* b_out = (const float*)d_in[13];

    float* out = (float*)d_out;               // [B,T,D] flat
    float* hn  = out + (size_t)M_ * D_;       // [B,L] appended

    // workspace layout (liveness-aliased, peak 192 MB)
    const size_t MB = 1u << 20;
    char* w = (char*)d_ws;
    u16*  xbf   = (u16*)(w + 0);        // [M,D] bf16 — dead after GEMM2
    u16*  wigb  = (u16*)(w + 0);        // [L,L]T bf16 — after xbf dead
    u16*  wagb  = (u16*)(w + 8*MB);
    u16*  zb    = (u16*)(w + 0);        // [M,L] bf16 — after gates
    u16*  ybf   = (u16*)(w + 32*MB);    // [M,L] bf16
    u16*  xbbf  = (u16*)(w + 64*MB);    // [M,L] bf16 — dead after conv
    u16*  woutb = (u16*)(w + 64*MB);    // after xbbf dead
    float* Pb   = (float*)(w + 72*MB);
    float* Sb   = (float*)(w + 73*MB);
    float* Hin  = (float*)(w + 74*MB);
    u16*  wyb   = (u16*)(w + 96*MB);    // weights dead after GEMM2
    u16*  wxb   = (u16*)(w + 104*MB);
    u16*  convb = (u16*)(w + 96*MB);    // [M,L] bf16 — after wyb/wxb dead
    u16*  abuf  = (u16*)(w + 128*MB);   // a   (written by GEMM_ag epilogue)
    u16*  nxbuf = (u16*)(w + 160*MB);   // nx  (written by GEMM_ig epilogue)

    const dim3 blk(256);
    const dim3 blkG(512);
    const dim3 gG((L_/128) * (M_/256));             // 512 blocks
    const dim3 gT(2048/32, 2048/32);                // transpose grids
    const int  gE8 = (M_ * L_ / 8) / 256;           // 8-wide elementwise
    const dim3 gScan(L_/256, CHUNKS, B_);
    const u16* nu = nullptr;

    // casts for stage 1
    hipLaunchKernelGGL(castx_kernel, dim3((M_*D_/4)/256), blk, 0, stream, x, xbf);
    hipLaunchKernelGGL(transcast_kernel, gT, blk, 0, stream, w_y, wyb, D_, L_);
    hipLaunchKernelGGL(transcast_kernel, gT, blk, 0, stream, w_x, wxb, D_, L_);
    // 1. y = GELU(x@w_y + b_y) -> ybf
    hipLaunchKernelGGL((mgemm_kernel<1, u16>), gG, blkG, 0, stream,
                       xbf, wyb, b_y, ybf, M_, L_, D_, nu, nu, (const float*)nullptr);
    // 2. xb = x@w_x + b_x -> xbbf
    hipLaunchKernelGGL((mgemm_kernel<0, u16>), gG, blkG, 0, stream,
                       xbf, wxb, b_x, xbbf, M_, L_, D_, nu, nu, (const float*)nullptr);
    // casts for stage 2 (xbf region now dead)
    hipLaunchKernelGGL(transcast_kernel, gT, blk, 0, stream, w_ig, wigb, L_, L_);
    hipLaunchKernelGGL(transcast_kernel, gT, blk, 0, stream, w_ag, wagb, L_, L_);
    // 3. conv(xbbf) -> convb (wyb/wxb region dead)
    hipLaunchKernelGGL(conv_kernel, dim3(gE8), blk, 0, stream, xbbf, cw, cb, convb);
    hipLaunchKernelGGL(transcast_kernel, gT, blk, 0, stream, w_out, woutb, L_, D_);  // xbbf dead
    // 4. gate_a GEMM + fused a-epilogue -> abuf
    hipLaunchKernelGGL((mgemm_kernel<3, u16>), gG, blkG, 0, stream,
                       convb, wagb, b_ag, abuf, M_, L_, L_, nu, nu, ap);
    // 5. gate_x GEMM + fused nx-epilogue (reads abuf, convb) -> nxbuf
    hipLaunchKernelGGL((mgemm_kernel<4, u16>), gG, blkG, 0, stream,
                       convb, wigb, b_ig, nxbuf, M_, L_, L_, abuf, convb, (const float*)nullptr);
    // 6-8. chunked scan; pass 3 fuses z = h*y -> zb
    hipLaunchKernelGGL(scan1_kernel, gScan, blk, 0, stream, abuf, nxbuf, Pb, Sb);
    hipLaunchKernelGGL(scan2_kernel, dim3(B_*L_/256), blk, 0, stream, Pb, Sb, Hin, hn);
    hipLaunchKernelGGL(scan3_kernel, gScan, blk, 0, stream, abuf, nxbuf, Hin, ybf, zb);
    // 9. out = z @ w_out + b_out -> d_out (f32)
    hipLaunchKernelGGL((mgemm_kernel<0, float>), gG, blkG, 0, stream,
                       zb, woutb, b_out, out, M_, D_, L_, nu, nu, (const float*)nullptr);
}

// Round 15
// 523.084 us; speedup vs baseline: 1.1408x; 1.1408x over previous
//
#include <hip/hip_runtime.h>
#include <math.h>

// Problem constants (fixed by the reference)
#define B_ 4
#define T_ 2048
#define D_ 2048
#define L_ 2048
#define KW 4
#define M_ (B_*T_)       // 8192 rows for all GEMMs

typedef unsigned short u16;
typedef unsigned short u16x8 __attribute__((ext_vector_type(8)));
typedef __bf16 bf16x8 __attribute__((ext_vector_type(8)));
typedef float f32x4 __attribute__((ext_vector_type(4)));

__device__ __forceinline__ u16 f2bf(float f) {       // RNE f32 -> bf16 bits
    unsigned u = __float_as_uint(f);
    u += 0x7fffu + ((u >> 16) & 1u);
    return (u16)(u >> 16);
}
__device__ __forceinline__ float bf2f(u16 h) {
    return __uint_as_float(((unsigned)h) << 16);
}
__device__ __forceinline__ float gelu_exact(float v) {
    return 0.5f * v * (1.0f + erff(v * 0.70710678118654752440f));
}
__device__ __forceinline__ float sigmoidf_(float v) {
    return 1.0f / (1.0f + __expf(-v));
}
__device__ __forceinline__ void gload16(const void* g, void* l) {
    __builtin_amdgcn_global_load_lds(
        (const __attribute__((address_space(1))) void*)g,
        (__attribute__((address_space(3))) void*)l,
        16, 0, 0);
}
__device__ __forceinline__ void bar() {
    __builtin_amdgcn_s_barrier();
}

// ---------------- cast x -> bf16 ----------------
__global__ __launch_bounds__(256)
void castx_kernel(const float* __restrict__ in, u16* __restrict__ out)
{
    const int i = blockIdx.x * 256 + threadIdx.x;      // one float4
    float4 v = ((const float4*)in)[i];
    ushort4 o;
    o.x = f2bf(v.x); o.y = f2bf(v.y); o.z = f2bf(v.z); o.w = f2bf(v.w);
    ((ushort4*)out)[i] = o;
}

// ---------------- transpose-cast weight [K,N] f32 -> [N,K] bf16 ----------------
__global__ __launch_bounds__(256)
void transcast_kernel(const float* __restrict__ in, u16* __restrict__ out,
                      int Kd, int Nd)
{
    __shared__ float tile[32][33];
    const int bx = blockIdx.x;          // along N
    const int by = blockIdx.y;          // along K
    const int tx = threadIdx.x & 31;
    const int ty = threadIdx.x >> 5;    // 0..7
    #pragma unroll
    for (int j = 0; j < 4; ++j) {
        const int r = by*32 + ty + j*8;
        tile[ty + j*8][tx] = in[(size_t)r * Nd + bx*32 + tx];
    }
    __syncthreads();
    #pragma unroll
    for (int j = 0; j < 4; ++j) {
        const int n = bx*32 + ty + j*8;
        out[(size_t)n * Kd + by*32 + tx] = f2bf(tile[tx][ty + j*8]);
    }
}

// =====================================================================
// bf16 MFMA GEMM — r12-verified structure (best measured: 86.4-90us,
// MfmaUtil 33-34%, 0 conflicts), RG-LRU fused as epilogues.
// C[M,N] = epi(A[M,K] @ BT[N,K]^T + bias)
// 256x128 tile, BK=32, 8 waves (4M x 2N), per-wave 64x64, 512 threads.
// LDS 72 KB 3-slot pipeline -> 2 blocks/CU; __launch_bounds__(512,4).
// Sync skeleton (r10 proven): prologue STAGE(0),STAGE(1); vmcnt(3)
// retires t0 BEFORE bar (cross-wave vis, r5 lesson); iter g: ds_read
// slot g%3 (8 b128) | STAGE(g+2) -> slot (g-1)%3 (reuse distance 3) |
// 16 MFMA | vmcnt(3) (tail: vmcnt(0)) | bar.
// Swizzle (verified 0 conflicts): stage pre-swizzled global slot
// (lane&3)^((lane>>3)&3) with linear LDS dest (rule 21); read slot
// q^((lr>>1)&3) -> 8 bank-quads x 8 lanes = b128 floor.
//
// EPI: 0 = bias (OutT=float or u16), 1 = gelu,
//      3 = RG-LRU "a":  g2=sig(v); a = (t==0)?0:exp(-8*g2*softplus(ap[col]))
//      4 = RG-LRU "nx": gx=sig(v); a=auxA[idx]; cv=auxC[idx];
//                       nx = gx*cv*sqrt(1-a^2)   (t==0: a==0 -> mult=1)
// Search ledger (r3-r14): schedule variants null; fences null (r8);
// 2 blocks/CU +5% (r10); 32x32 shape -9% bank-conflict (r13); dual-B
// fusion -18% L2 thrash (r11); in-wave frag pipelining -12% (r14);
// epilogue fusion +9% (r12, kept). This config is the search optimum.
// =====================================================================
__device__ __forceinline__ void store_out(float* C, size_t idx, float v) { C[idx] = v; }
__device__ __forceinline__ void store_out(u16*   C, size_t idx, float v) { C[idx] = f2bf(v); }

template<int EPI, typename OutT>
__global__ __launch_bounds__(512, 4)
void mgemm_kernel(const u16* __restrict__ A, const u16* __restrict__ BT,
                  const float* __restrict__ bias, OutT* __restrict__ C,
                  int M, int N, int K,
                  const u16* __restrict__ auxA,   // EPI=4: a buffer
                  const u16* __restrict__ auxC,   // EPI=4: conv buffer
                  const float* __restrict__ ap)   // EPI=3: a_param
{
    __shared__ __align__(16) u16 lds[36864];   // A: 3x8192 u16 | B: 3x4096 u16 = 72 KB
    u16* ldsB = lds + 24576;

    const int tid  = threadIdx.x;
    const int wave = tid >> 6;          // 0..7
    const int lane = tid & 63;

    // bijective XCD swizzle (nwg = 512, %8 == 0)
    const int nbx = N >> 7;                       // N/128
    const int nwg = nbx * (M >> 8);
    const int bid = blockIdx.x;
    const int li  = (bid & 7) * (nwg >> 3) + (bid >> 3);
    const int bm  = (li / nbx) * 256;
    const int bn  = (li % nbx) * 128;

    const int wr = wave >> 1;           // 0..3 (M quarter: 64 rows)
    const int wn = wave & 1;            // 0..1 (N half: 64 cols)
    const int lr = lane & 15;
    const int q  = lane >> 4;

    const int grow  = lane >> 2;                       // row within chunk
    const int gslot = (lane & 3) ^ ((lane >> 3) & 3);  // pre-swizzled k-slot
    const u16* gA0 = A  + (size_t)(bm + wave*16     + grow) * K + gslot*8;
    const u16* gA1 = A  + (size_t)(bm + (wave+8)*16 + grow) * K + gslot*8;
    const u16* gB0 = BT + (size_t)(bn + wave*16     + grow) * K + gslot*8;
    const int dA0 = wave*512     + lane*8;
    const int dA1 = (wave+8)*512 + lane*8;
    const int dB0 = wave*512     + lane*8;

    auto STAGE = [&](int g) {
        const int s = g % 3;
        const size_t kg = (size_t)g << 5;
        u16* a = lds  + s*8192;
        u16* b = ldsB + s*4096;
        gload16(gA0 + kg, &a[dA0]);
        gload16(gA1 + kg, &a[dA1]);
        gload16(gB0 + kg, &b[dB0]);
    };

    const int ksw = (q ^ ((lr >> 1) & 3)) * 8;   // read-side swizzled k-slot

    f32x4 acc[4][4] = {};

    STAGE(0); STAGE(1);
    asm volatile("s_waitcnt vmcnt(3)" ::: "memory");   // retire tile 0 (before bar)
    bar();

    const int NT = K >> 5;              // 64 K-tiles
    for (int g = 0; g < NT; ++g) {
        const int s = g % 3;
        const u16* Ab = lds  + s*8192;
        const u16* Bb = ldsB + s*4096;

        bf16x8 a[4], b[4];
        #pragma unroll
        for (int i = 0; i < 4; ++i)
            a[i] = *(const bf16x8*)&Ab[(wr*64 + i*16 + lr)*32 + ksw];
        #pragma unroll
        for (int j = 0; j < 4; ++j)
            b[j] = *(const bf16x8*)&Bb[(wn*64 + j*16 + lr)*32 + ksw];

        if (g + 2 < NT) STAGE(g + 2);   // slot (g+2)%3 == (g-1)%3: safe (ledger)

        __builtin_amdgcn_s_setprio(1);
        #pragma unroll
        for (int i = 0; i < 4; ++i)
            #pragma unroll
            for (int j = 0; j < 4; ++j)
                acc[i][j] = __builtin_amdgcn_mfma_f32_16x16x32_bf16(a[i], b[j], acc[i][j], 0, 0, 0);
        __builtin_amdgcn_s_setprio(0);

        if (g + 2 < NT)      { asm volatile("s_waitcnt vmcnt(3)" ::: "memory"); }
        else if (g + 1 < NT) { asm volatile("s_waitcnt vmcnt(0)" ::: "memory"); }
        bar();
    }

    // ---- epilogue; C/D layout: col = lane&15, row = (lane>>4)*4 + reg ----
    const int orow = (lane >> 4) * 4;
    float bv[4], spv[4];
    #pragma unroll
    for (int nj = 0; nj < 4; ++nj) {
        const int col = bn + wn*64 + nj*16 + lr;
        bv[nj] = bias[col];
        if (EPI == 3) spv[nj] = log1pf(expf(ap[col]));   // softplus(a_param)
    }
    #pragma unroll
    for (int mi = 0; mi < 4; ++mi) {
        #pragma unroll
        for (int r = 0; r < 4; ++r) {
            const int row = bm + wr*64 + mi*16 + orow + r;
            const size_t rb = (size_t)row * N + bn + wn*64 + lr;
            const int t = row & (T_ - 1);
            #pragma unroll
            for (int nj = 0; nj < 4; ++nj) {
                float v = acc[mi][nj][r] + bv[nj];
                if (EPI == 1) {
                    v = gelu_exact(v);
                } else if (EPI == 3) {
                    const float g2 = sigmoidf_(v);
                    v = (t == 0) ? 0.f : expf(-8.0f * g2 * spv[nj]);
                } else if (EPI == 4) {
                    const float gx = sigmoidf_(v);
                    const float av = bf2f(auxA[rb + nj*16]);
                    const float cv = bf2f(auxC[rb + nj*16]);
                    v = gx * cv * sqrtf(fmaxf(0.f, 1.0f - av*av));
                }
                store_out(C, rb + nj*16, v);
            }
        }
    }
}

// ---------------- causal depthwise conv1d, width 4 (bf16 in/out) ----------------
__global__ __launch_bounds__(256)
void conv_kernel(const u16* __restrict__ xb, const float* __restrict__ cw,
                 const float* __restrict__ cb, u16* __restrict__ out)
{
    const int idx = blockIdx.x * 256 + threadIdx.x;    // one 8-elem chunk
    const int NL8 = L_ / 8;
    const int l = (idx % NL8) * 8;
    const int bt = idx / NL8;
    const int t = bt & (T_ - 1);
    float acc[8];
    #pragma unroll
    for (int j = 0; j < 8; ++j) acc[j] = cb[l + j];
    #pragma unroll
    for (int k = 0; k < KW; ++k) {
        const int ts = t - (KW-1) + k;
        if (ts >= 0) {
            u16x8 xv = *(const u16x8*)(xb + ((size_t)(bt - (KW-1-k))) * L_ + l);
            #pragma unroll
            for (int j = 0; j < 8; ++j)
                acc[j] = fmaf(cw[k*L_ + l + j], bf2f(xv[j]), acc[j]);
        }
    }
    u16x8 o;
    #pragma unroll
    for (int j = 0; j < 8; ++j) o[j] = f2bf(acc[j]);
    *(u16x8*)(out + (size_t)bt * L_ + l) = o;
}

// ---------------- chunked linear scan: h_t = a_t*h_{t-1} + x_t ----------------
#define CHUNKS 32
#define CLEN (T_ / CHUNKS)   // 64

__global__ __launch_bounds__(256)
void scan1_kernel(const u16* __restrict__ Ab, const u16* __restrict__ Xb,
                  float* __restrict__ Pb, float* __restrict__ Sb)
{
    const int l = blockIdx.x * 256 + threadIdx.x;
    const int c = blockIdx.y;
    const int b = blockIdx.z;
    size_t base = ((size_t)b * T_ + (size_t)c * CLEN) * L_ + l;
    float h = 0.f, P = 1.f;
    #pragma unroll 4
    for (int t = 0; t < CLEN; ++t) {
        float a = bf2f(Ab[base + (size_t)t * L_]);
        float x = bf2f(Xb[base + (size_t)t * L_]);
        h = fmaf(a, h, x);
        P *= a;
    }
    const size_t o = ((size_t)b * CHUNKS + c) * L_ + l;
    Pb[o] = P;
    Sb[o] = h;
}

__global__ __launch_bounds__(256)
void scan2_kernel(const float* __restrict__ Pb, const float* __restrict__ Sb,
                  float* __restrict__ Hin, float* __restrict__ hn)
{
    const int idx = blockIdx.x * 256 + threadIdx.x;  // B*L threads
    const int l = idx & (L_ - 1);
    const int b = idx >> 11;
    float h = 0.f;
    for (int c = 0; c < CHUNKS; ++c) {
        const size_t o = ((size_t)b * CHUNKS + c) * L_ + l;
        Hin[o] = h;
        h = fmaf(Pb[o], h, Sb[o]);
    }
    hn[(size_t)b * L_ + l] = h;
}

__global__ __launch_bounds__(256)
void scan3_kernel(const u16* __restrict__ Ab, const u16* __restrict__ Xb,
                  const float* __restrict__ Hin, const u16* __restrict__ Yb,
                  u16* __restrict__ Zb)
{
    const int l = blockIdx.x * 256 + threadIdx.x;
    const int c = blockIdx.y;
    const int b = blockIdx.z;
    float h = Hin[((size_t)b * CHUNKS + c) * L_ + l];
    size_t base = ((size_t)b * T_ + (size_t)c * CLEN) * L_ + l;
    #pragma unroll 4
    for (int t = 0; t < CLEN; ++t) {
        const size_t o = base + (size_t)t * L_;
        h = fmaf(bf2f(Ab[o]), h, bf2f(Xb[o]));
        Zb[o] = f2bf(h * bf2f(Yb[o]));
    }
}

// ---------------- launch ----------------
extern "C" void kernel_launch(void* const* d_in, const int* in_sizes, int n_in,
                              void* d_out, int out_size, void* d_ws, size_t ws_size,
                              hipStream_t stream)
{
    const float* x     = (const float*)d_in[0];
    const float* w_y   = (const float*)d_in[1];
    const float* b_y   = (const float*)d_in[2];
    const float* w_x   = (const float*)d_in[3];
    const float* b_x   = (const float*)d_in[4];
    const float* cw    = (const float*)d_in[5];
    const float* cb    = (const float*)d_in[6];
    const float* ap    = (const float*)d_in[7];
    const float* w_ig  = (const float*)d_in[8];
    const float* b_ig  = (const float*)d_in[9];
    const float* w_ag  = (const float*)d_in[10];
    const float* b_ag  = (const float*)d_in[11];
    const float* w_out = (const float*)d_in[12];
    const float* b_out = (const float*)d_in[13];

    float* out = (float*)d_out;               // [B,T,D] flat
    float* hn  = out + (size_t)M_ * D_;       // [B,L] appended

    // workspace layout (liveness-aliased, peak 192 MB)
    const size_t MB = 1u << 20;
    char* w = (char*)d_ws;
    u16*  xbf   = (u16*)(w + 0);        // [M,D] bf16 — dead after GEMM2
    u16*  wigb  = (u16*)(w + 0);        // [L,L]T bf16 — after xbf dead
    u16*  wagb  = (u16*)(w + 8*MB);
    u16*  zb    = (u16*)(w + 0);        // [M,L] bf16 — after gates
    u16*  ybf   = (u16*)(w + 32*MB);    // [M,L] bf16
    u16*  xbbf  = (u16*)(w + 64*MB);    // [M,L] bf16 — dead after conv
    u16*  woutb = (u16*)(w + 64*MB);    // after xbbf dead
    float* Pb   = (float*)(w + 72*MB);
    float* Sb   = (float*)(w + 73*MB);
    float* Hin  = (float*)(w + 74*MB);
    u16*  wyb   = (u16*)(w + 96*MB);    // weights dead after GEMM2
    u16*  wxb   = (u16*)(w + 104*MB);
    u16*  convb = (u16*)(w + 96*MB);    // [M,L] bf16 — after wyb/wxb dead
    u16*  abuf  = (u16*)(w + 128*MB);   // a   (written by GEMM_ag epilogue)
    u16*  nxbuf = (u16*)(w + 160*MB);   // nx  (written by GEMM_ig epilogue)

    const dim3 blk(256);
    const dim3 blkG(512);
    const dim3 gG((L_/128) * (M_/256));             // 512 blocks -> 2/CU resident
    const dim3 gT(2048/32, 2048/32);                // transpose grids
    const int  gE8 = (M_ * L_ / 8) / 256;           // 8-wide elementwise
    const dim3 gScan(L_/256, CHUNKS, B_);
    const u16* nu = nullptr;

    // casts for stage 1
    hipLaunchKernelGGL(castx_kernel, dim3((M_*D_/4)/256), blk, 0, stream, x, xbf);
    hipLaunchKernelGGL(transcast_kernel, gT, blk, 0, stream, w_y, wyb, D_, L_);
    hipLaunchKernelGGL(transcast_kernel, gT, blk, 0, stream, w_x, wxb, D_, L_);
    // 1. y = GELU(x@w_y + b_y) -> ybf
    hipLaunchKernelGGL((mgemm_kernel<1, u16>), gG, blkG, 0, stream,
                       xbf, wyb, b_y, ybf, M_, L_, D_, nu, nu, (const float*)nullptr);
    // 2. xb = x@w_x + b_x -> xbbf
    hipLaunchKernelGGL((mgemm_kernel<0, u16>), gG, blkG, 0, stream,
                       xbf, wxb, b_x, xbbf, M_, L_, D_, nu, nu, (const float*)nullptr);
    // casts for stage 2 (xbf region now dead)
    hipLaunchKernelGGL(transcast_kernel, gT, blk, 0, stream, w_ig, wigb, L_, L_);
    hipLaunchKernelGGL(transcast_kernel, gT, blk, 0, stream, w_ag, wagb, L_, L_);
    // 3. conv(xbbf) -> convb (wyb/wxb region dead)
    hipLaunchKernelGGL(conv_kernel, dim3(gE8), blk, 0, stream, xbbf, cw, cb, convb);
    hipLaunchKernelGGL(transcast_kernel, gT, blk, 0, stream, w_out, woutb, L_, D_);  // xbbf dead
    // 4. gate_a GEMM + fused a-epilogue -> abuf
    hipLaunchKernelGGL((mgemm_kernel<3, u16>), gG, blkG, 0, stream,
                       convb, wagb, b_ag, abuf, M_, L_, L_, nu, nu, ap);
    // 5. gate_x GEMM + fused nx-epilogue (reads abuf, convb) -> nxbuf
    hipLaunchKernelGGL((mgemm_kernel<4, u16>), gG, blkG, 0, stream,
                       convb, wigb, b_ig, nxbuf, M_, L_, L_, abuf, convb, (const float*)nullptr);
    // 6-8. chunked scan; pass 3 fuses z = h*y -> zb
    hipLaunchKernelGGL(scan1_kernel, gScan, blk, 0, stream, abuf, nxbuf, Pb, Sb);
    hipLaunchKernelGGL(scan2_kernel, dim3(B_*L_/256), blk, 0, stream, Pb, Sb, Hin, hn);
    hipLaunchKernelGGL(scan3_kernel, gScan, blk, 0, stream, abuf, nxbuf, Hin, ybf, zb);
    // 9. out = z @ w_out + b_out -> d_out (f32)
    hipLaunchKernelGGL((mgemm_kernel<0, float>), gG, blkG, 0, stream,
                       zb, woutb, b_out, out, M_, D_, L_, nu, nu, (const float*)nullptr);
}